// Round 14
// baseline (129.324 us; speedup 1.0000x reference)
//
#include <hip/hip_runtime.h>

#define N_NODES 100000
#define D 128

typedef unsigned short ushort_t;
typedef unsigned char uchar_t;
typedef __attribute__((ext_vector_type(8))) short short8;
typedef __attribute__((ext_vector_type(4))) float f32x4;

// round-to-nearest-even f32 -> bf16 bits (finite inputs)
__device__ __forceinline__ unsigned f2bf(float x) {
    unsigned u = __float_as_uint(x);
    return (u + 0x7fffu + ((u >> 16) & 1u)) >> 16;
}

// ---------------------------------------------------------------------------
// Kernel 1: W -> MFMA A-fragment-ordered bf16 (Wfrag).
// ---------------------------------------------------------------------------
__global__ __launch_bounds__(64)
void build_wfrag_kernel(const float* __restrict__ W,
                        ushort_t* __restrict__ Wfrag) {
    const int t  = blockIdx.x;      // 0..31 = jt*4 + kt
    const int jt = t >> 2, kt = t & 3;
    const int l  = threadIdx.x;
    const float* src = W + (size_t)(jt * 16 + (l & 15)) * D + kt * 32 + (l >> 4) * 8;
    const float4 p0 = *reinterpret_cast<const float4*>(src);
    const float4 p1 = *reinterpret_cast<const float4*>(src + 4);
    uint4 o;
    o.x = f2bf(p0.x) | (f2bf(p0.y) << 16);
    o.y = f2bf(p0.z) | (f2bf(p0.w) << 16);
    o.z = f2bf(p1.x) | (f2bf(p1.y) << 16);
    o.w = f2bf(p1.z) | (f2bf(p1.w) << 16);
    *reinterpret_cast<uint4*>(Wfrag + ((size_t)t * 64 + l) * 8) = o;
}

// ---------------------------------------------------------------------------
// Kernel 2: G = H @ W^T via MFMA, quantized per-node to uint8 (+128 bias):
//   Gq[node][j] = round(g/s) + 128, s = scales[node] = rowmax|g|/127.
// Row = 128 B = ONE cache line per edge in the gather.
// ---------------------------------------------------------------------------
__global__ __launch_bounds__(256)
void gemm_Gq_kernel(const float* __restrict__ h,
                    const ushort_t* __restrict__ Wfrag,
                    uchar_t* __restrict__ Gq,
                    float* __restrict__ scales) {
    const int wave = threadIdx.x >> 6;
    const int l    = threadIdx.x & 63;
    const int tile = blockIdx.x * 4 + wave;
    if (tile >= N_NODES / 16) return;
    const int n0   = tile * 16;
    const int lrow = l & 15;
    const int lk   = l >> 4;

    union { short8 v; ushort_t u[8]; } bfrag[4];
    const float* hp = h + (size_t)(n0 + lrow) * D + lk * 8;
#pragma unroll
    for (int kt = 0; kt < 4; ++kt) {
        const float4 q0 = *reinterpret_cast<const float4*>(hp + kt * 32);
        const float4 q1 = *reinterpret_cast<const float4*>(hp + kt * 32 + 4);
        bfrag[kt].u[0] = (ushort_t)f2bf(q0.x);
        bfrag[kt].u[1] = (ushort_t)f2bf(q0.y);
        bfrag[kt].u[2] = (ushort_t)f2bf(q0.z);
        bfrag[kt].u[3] = (ushort_t)f2bf(q0.w);
        bfrag[kt].u[4] = (ushort_t)f2bf(q1.x);
        bfrag[kt].u[5] = (ushort_t)f2bf(q1.y);
        bfrag[kt].u[6] = (ushort_t)f2bf(q1.z);
        bfrag[kt].u[7] = (ushort_t)f2bf(q1.w);
    }

    const uint4* wf = reinterpret_cast<const uint4*>(Wfrag) + l;
    f32x4 acc[8];
#pragma unroll
    for (int jt = 0; jt < 8; ++jt) {
        acc[jt] = (f32x4){0.f, 0.f, 0.f, 0.f};
#pragma unroll
        for (int kt = 0; kt < 4; ++kt) {
            union { uint4 q; short8 v; } af;
            af.q = wf[(jt * 4 + kt) * 64];
            acc[jt] = __builtin_amdgcn_mfma_f32_16x16x32_bf16(
                af.v, bfrag[kt].v, acc[jt], 0, 0, 0);
        }
    }

    float amax = 0.f;
#pragma unroll
    for (int jt = 0; jt < 8; ++jt) {
#pragma unroll
        for (int r = 0; r < 4; ++r) amax = fmaxf(amax, fabsf(acc[jt][r]));
    }
    amax = fmaxf(amax, __shfl_xor(amax, 16));
    amax = fmaxf(amax, __shfl_xor(amax, 32));
    const float s   = amax > 0.f ? amax * (1.f / 127.f) : 1.f;
    const float inv = amax > 0.f ? 127.f / amax : 0.f;

#pragma unroll
    for (int jt = 0; jt < 8; ++jt) {
        const unsigned q0 = (unsigned)((int)rintf(acc[jt][0] * inv) + 128);
        const unsigned q1 = (unsigned)((int)rintf(acc[jt][1] * inv) + 128);
        const unsigned q2 = (unsigned)((int)rintf(acc[jt][2] * inv) + 128);
        const unsigned q3 = (unsigned)((int)rintf(acc[jt][3] * inv) + 128);
        const unsigned pk = q0 | (q1 << 8) | (q2 << 16) | (q3 << 24);
        *reinterpret_cast<unsigned*>(
            Gq + (size_t)(n0 + lrow) * D + jt * 16 + lk * 4) = pk;
    }
    if (l < 16) scales[n0 + l] = s;
}

// ---------------------------------------------------------------------------
// Kernel 3 (prep sweep): per edge e, (a) boundary-detect row_ptr from the
// SORTED edge_rows, (b) pairs[e] = {cols[e], bits(vals[e]*scales[cols[e]])}
// (one 8B load per edge in the gather instead of two 4B loads).
// ---------------------------------------------------------------------------
__global__ __launch_bounds__(256)
void prep_kernel(const int* __restrict__ rows,
                 const int* __restrict__ cols,
                 const float* __restrict__ vals,
                 const float* __restrict__ scales,
                 int* __restrict__ row_ptr,
                 int2* __restrict__ pairs, int n_edges) {
    const int e = blockIdx.x * 256 + threadIdx.x;
    if (e >= n_edges) return;

    const int c = cols[e];
    pairs[e] = make_int2(c, __float_as_int(vals[e] * scales[c]));

    const int r0 = rows[e];
    if (e == 0) {
        for (int r = 0; r <= r0; ++r) row_ptr[r] = 0;
    }
    if (e + 1 < n_edges) {
        const int r1 = rows[e + 1];
        for (int r = r0 + 1; r <= r1; ++r) row_ptr[r] = e + 1;
    } else {
        for (int r = r0 + 1; r <= N_NODES; ++r) row_ptr[r] = n_edges;
    }
}

// ---------------------------------------------------------------------------
// Kernel 4: out = relu(S @ dequant(Gq) + b). ONE NODE PER 8-LANE GROUP:
// lane il (0..7) owns feats il*16..il*16+15; Gq row = 8 lanes x uint4 (16B)
// = 128B = one line, and each wave-level load touches 8 DISTINCT lines
// (2x the 16-lane variant) -> 64 lines in flight/wave at 8-deep.
// (col,val) read as one packed 8B int2 per edge.
// ---------------------------------------------------------------------------
__device__ __forceinline__ void accq16(float* a, float& vsum, float vs,
                                       uint4 g) {
    const unsigned w[4] = {g.x, g.y, g.z, g.w};
#pragma unroll
    for (int k = 0; k < 4; ++k) {
        a[4 * k + 0] += vs * (float)(w[k] & 0xffu);
        a[4 * k + 1] += vs * (float)((w[k] >> 8) & 0xffu);
        a[4 * k + 2] += vs * (float)((w[k] >> 16) & 0xffu);
        a[4 * k + 3] += vs * (float)(w[k] >> 24);
    }
    vsum += vs;
}

__global__ __launch_bounds__(256)
void gconv_gather_g8_kernel(const int2* __restrict__ pairs,
                            const uchar_t* __restrict__ Gq,
                            const float* __restrict__ bias,
                            const int* __restrict__ row_ptr,
                            float* __restrict__ out) {
    const int tid  = blockIdx.x * 256 + threadIdx.x;
    const int node = tid >> 3;
    const int il   = tid & 7;
    const unsigned il16 = (unsigned)il * 16u;

    int e = row_ptr[node];
    const int end = row_ptr[node + 1];

    float a[16];
#pragma unroll
    for (int j = 0; j < 16; ++j) a[j] = 0.f;
    float vsum = 0.f;

    for (; e + 7 < end; e += 8) {
        int2  p[8];
        uint4 g[8];
#pragma unroll
        for (int i = 0; i < 8; ++i) p[i] = pairs[e + i];
#pragma unroll
        for (int i = 0; i < 8; ++i)
            g[i] = *reinterpret_cast<const uint4*>(
                Gq + (((unsigned)p[i].x << 7) + il16));
#pragma unroll
        for (int i = 0; i < 8; ++i)
            accq16(a, vsum, __int_as_float(p[i].y), g[i]);
    }
    for (; e < end; ++e) {
        const int2 p = pairs[e];
        const uint4 g = *reinterpret_cast<const uint4*>(
            Gq + (((unsigned)p.x << 7) + il16));
        accq16(a, vsum, __int_as_float(p.y), g);
    }

    const float corr = 128.f * vsum;
    float* op = out + (size_t)node * D + il16;
#pragma unroll
    for (int q = 0; q < 4; ++q) {
        const float4 bb = *reinterpret_cast<const float4*>(bias + il16 + q * 4);
        f32x4 r;
        r[0] = a[4 * q + 0] - corr + bb.x;
        r[1] = a[4 * q + 1] - corr + bb.y;
        r[2] = a[4 * q + 2] - corr + bb.z;
        r[3] = a[4 * q + 3] - corr + bb.w;
#pragma unroll
        for (int i = 0; i < 4; ++i) r[i] = r[i] > 0.f ? r[i] : 0.f;
        *reinterpret_cast<f32x4*>(op + q * 4) = r;
    }
}

// ---------------------------------------------------------------------------
extern "C" void kernel_launch(void* const* d_in, const int* in_sizes, int n_in,
                              void* d_out, int out_size, void* d_ws,
                              size_t ws_size, hipStream_t stream) {
    const int*   edge_rows = (const int*)d_in[0];
    const int*   edge_cols = (const int*)d_in[1];
    const float* edge_vals = (const float*)d_in[2];
    const float* h         = (const float*)d_in[3];
    const float* W         = (const float*)d_in[4];
    const float* b         = (const float*)d_in[5];
    float*       out       = (float*)d_out;

    const int n_edges = in_sizes[0];

    // ws: [Wfrag 32K|pad64K][row_ptr 400K|pad512K][scales 400K|pad512K]
    //     [Gq 12.8M][pairs 25.6M]   total ~40MB (ws proven >=65MB in R10)
    const size_t OFF_RP = 64 * 1024;
    const size_t OFF_SC = OFF_RP + 512 * 1024;
    const size_t OFF_GQ = OFF_SC + 512 * 1024;
    const size_t OFF_PR = OFF_GQ + (size_t)N_NODES * D;

    ushort_t* Wfrag   = (ushort_t*)d_ws;
    int*      row_ptr = (int*)((char*)d_ws + OFF_RP);
    float*    scales  = (float*)((char*)d_ws + OFF_SC);
    uchar_t*  Gq      = (uchar_t*)((char*)d_ws + OFF_GQ);
    int2*     pairs   = (int2*)((char*)d_ws + OFF_PR);

    build_wfrag_kernel<<<32, 64, 0, stream>>>(W, Wfrag);

    const int n_tiles     = N_NODES / 16;  // 6250
    const int gemm_blocks = (n_tiles + 3) / 4;
    gemm_Gq_kernel<<<gemm_blocks, 256, 0, stream>>>(h, Wfrag, Gq, scales);

    prep_kernel<<<(n_edges + 255) / 256, 256, 0, stream>>>(
        edge_rows, edge_cols, edge_vals, scales, row_ptr, pairs, n_edges);

    const int gather_blocks = N_NODES * 8 / 256;  // 3125
    gconv_gather_g8_kernel<<<gather_blocks, 256, 0, stream>>>(
        pairs, Gq, b, row_ptr, out);
}